// Round 1
// baseline (224.555 us; speedup 1.0000x reference)
//
#include <hip/hip_runtime.h>
#include <math.h>

#define NB 32
#define LQ 2048
#define LK 2048
#define HD 1024
#define AD 512
#define QCH 16   // q-chunks for first-stage query reduction

// ---------------- K1: partial[qc][b][h] = sum over q-chunk of query ----------------
__global__ void k1_qreduce(const float* __restrict__ query, float* __restrict__ partial) {
    int bid = blockIdx.x;            // NB*QCH blocks
    int b = bid / QCH, qc = bid % QCH;
    int t = threadIdx.x;             // 256 threads, each one float4 column -> covers HD=1024
    const int QPC = LQ / QCH;        // 128 rows per chunk
    float4 acc = {0.f, 0.f, 0.f, 0.f};
    const float4* src = (const float4*)(query + (size_t)b * LQ * HD + (size_t)qc * QPC * HD);
    for (int q = 0; q < QPC; ++q) {
        float4 v = src[(size_t)q * (HD / 4) + t];
        acc.x += v.x; acc.y += v.y; acc.z += v.z; acc.w += v.w;
    }
    float4* dst = (float4*)(partial + ((size_t)qc * NB + b) * HD);
    dst[t] = acc;
}

// ---------------- K2: s_q[b][h] = sum over qc of partial ----------------
__global__ void k2_qreduce2(const float* __restrict__ partial, float* __restrict__ s_q) {
    int t = blockIdx.x * blockDim.x + threadIdx.x;   // NB*HD = 32768
    float acc = 0.f;
    for (int qc = 0; qc < QCH; ++qc) acc += partial[(size_t)qc * NB * HD + t];
    s_q[t] = acc;
}

// ---------------- K3: qsum[b][a] = s_q[b]·Wq[:,a] + LQ*bq[a] ----------------
__global__ void k3_qsum(const float* __restrict__ s_q, const float* __restrict__ Wq,
                        const float* __restrict__ bq, float* __restrict__ qsum) {
    int t = blockIdx.x * blockDim.x + threadIdx.x;   // NB*AD = 16384
    int b = t / AD, a = t % AD;
    double acc = (double)LQ * (double)bq[a];
    const float* sr = s_q + (size_t)b * HD;
    for (int h = 0; h < HD; ++h) acc += (double)sr[h] * (double)Wq[(size_t)h * AD + a];
    qsum[t] = (float)acc;
}

// ---------------- K4: wk_eff[b][h] = qsum[b]·Wk[h,:]; wv_eff[h] = Wk[h,:]·Wv; c_v ----------------
__global__ void k4_weff(const float* __restrict__ qsum, const float* __restrict__ Wk,
                        const float* __restrict__ Wv, const float* __restrict__ bk,
                        const float* __restrict__ bv,
                        float* __restrict__ wk_eff, float* __restrict__ wv_eff,
                        float* __restrict__ c_v) {
    int t = blockIdx.x * blockDim.x + threadIdx.x;   // NB*HD = 32768
    int b = t / HD, h = t % HD;
    const float* qs = qsum + (size_t)b * AD;
    const float* wr = Wk + (size_t)h * AD;
    double acc = 0.0;
    for (int a = 0; a < AD; ++a) acc += (double)qs[a] * (double)wr[a];
    wk_eff[t] = (float)acc;
    if (b == 0) {
        double av = 0.0;
        for (int a = 0; a < AD; ++a) av += (double)wr[a] * (double)Wv[a];
        wv_eff[h] = (float)av;
        if (h == 0) {
            double c = (double)bv[0];
            for (int a = 0; a < AD; ++a) c += (double)bk[a] * (double)Wv[a];
            c_v[0] = (float)c;
        }
    }
}

// ---------------- K5: per (b,k): scores = key·wk_eff[b], vvals = key·wv_eff + c_v ----------------
__global__ void k5_scores(const float* __restrict__ key, const float* __restrict__ wk_eff,
                          const float* __restrict__ wv_eff, const float* __restrict__ c_v,
                          float* __restrict__ scores, float* __restrict__ vvals) {
    __shared__ float lwk[HD];
    __shared__ float lwv[HD];
    int bid = blockIdx.x;            // NB*LK/4 = 16384 blocks, 4 waves each
    int pair0 = bid * 4;
    int b = pair0 / LK;              // all 4 waves share b (LK % 4 == 0)
    for (int i = threadIdx.x; i < HD; i += 256) {
        lwk[i] = wk_eff[(size_t)b * HD + i];
        lwv[i] = wv_eff[i];
    }
    __syncthreads();
    int w = threadIdx.x >> 6;
    int lane = threadIdx.x & 63;
    int pair = pair0 + w;
    int k = pair & (LK - 1);
    const float4* kr = (const float4*)(key + ((size_t)b * LK + k) * HD);
    double sc = 0.0, vv = 0.0;
    #pragma unroll
    for (int j = 0; j < 4; ++j) {
        int f = lane + 64 * j;       // float4 index 0..255
        float4 kv = kr[f];
        int e = f * 4;
        sc += (double)kv.x * (double)lwk[e]     + (double)kv.y * (double)lwk[e + 1]
            + (double)kv.z * (double)lwk[e + 2] + (double)kv.w * (double)lwk[e + 3];
        vv += (double)kv.x * (double)lwv[e]     + (double)kv.y * (double)lwv[e + 1]
            + (double)kv.z * (double)lwv[e + 2] + (double)kv.w * (double)lwv[e + 3];
    }
    #pragma unroll
    for (int off = 32; off > 0; off >>= 1) {
        sc += __shfl_down(sc, off);
        vv += __shfl_down(vv, off);
    }
    if (lane == 0) {
        scores[pair] = (float)sc;
        vvals[pair]  = (float)(vv + (double)c_v[0]);
    }
}

// ---------------- K6: per b: softmax over scores, weighted sum of vvals ----------------
__global__ void k6_softmax(const float* __restrict__ scores, const float* __restrict__ vvals,
                           float* __restrict__ out) {
    int b = blockIdx.x;
    int t = threadIdx.x;             // 256
    __shared__ float smax_sh[4];
    __shared__ double num_sh[4], den_sh[4];
    const float* sr = scores + (size_t)b * LK;
    const float* vr = vvals  + (size_t)b * LK;
    float m = -INFINITY;
    for (int k = t; k < LK; k += 256) m = fmaxf(m, sr[k]);
    #pragma unroll
    for (int off = 32; off > 0; off >>= 1) m = fmaxf(m, __shfl_down(m, off));
    int w = t >> 6, lane = t & 63;
    if (lane == 0) smax_sh[w] = m;
    __syncthreads();
    float gm = fmaxf(fmaxf(smax_sh[0], smax_sh[1]), fmaxf(smax_sh[2], smax_sh[3]));
    double num = 0.0, den = 0.0;
    for (int k = t; k < LK; k += 256) {
        double e = exp((double)(sr[k] - gm));
        den += e;
        num += e * (double)vr[k];
    }
    #pragma unroll
    for (int off = 32; off > 0; off >>= 1) {
        num += __shfl_down(num, off);
        den += __shfl_down(den, off);
    }
    if (lane == 0) { num_sh[w] = num; den_sh[w] = den; }
    __syncthreads();
    if (t == 0) {
        double N = num_sh[0] + num_sh[1] + num_sh[2] + num_sh[3];
        double D = den_sh[0] + den_sh[1] + den_sh[2] + den_sh[3];
        out[b] = (float)(N / D);
    }
}

extern "C" void kernel_launch(void* const* d_in, const int* in_sizes, int n_in,
                              void* d_out, int out_size, void* d_ws, size_t ws_size,
                              hipStream_t stream) {
    const float* query = (const float*)d_in[0];
    const float* key   = (const float*)d_in[1];
    const float* Wq    = (const float*)d_in[2];
    const float* bq    = (const float*)d_in[3];
    const float* Wk    = (const float*)d_in[4];
    const float* bk    = (const float*)d_in[5];
    const float* Wv    = (const float*)d_in[6];
    const float* bv    = (const float*)d_in[7];
    float* out = (float*)d_out;

    float* ws = (float*)d_ws;
    size_t off = 0;
    float* partial = ws + off; off += (size_t)QCH * NB * HD;  // 524288
    float* s_q     = ws + off; off += (size_t)NB * HD;        // 32768
    float* qsum    = ws + off; off += (size_t)NB * AD;        // 16384
    float* wk_eff  = ws + off; off += (size_t)NB * HD;        // 32768
    float* wv_eff  = ws + off; off += (size_t)HD;             // 1024
    float* c_v     = ws + off; off += 1;
    float* scores  = ws + off; off += (size_t)NB * LK;        // 65536
    float* vvals   = ws + off; off += (size_t)NB * LK;        // 65536

    hipLaunchKernelGGL(k1_qreduce, dim3(NB * QCH), dim3(256), 0, stream, query, partial);
    hipLaunchKernelGGL(k2_qreduce2, dim3(NB * HD / 256), dim3(256), 0, stream, partial, s_q);
    hipLaunchKernelGGL(k3_qsum, dim3(NB * AD / 256), dim3(256), 0, stream, s_q, Wq, bq, qsum);
    hipLaunchKernelGGL(k4_weff, dim3(NB * HD / 256), dim3(256), 0, stream,
                       qsum, Wk, Wv, bk, bv, wk_eff, wv_eff, c_v);
    hipLaunchKernelGGL(k5_scores, dim3(NB * LK / 4), dim3(256), 0, stream,
                       key, wk_eff, wv_eff, c_v, scores, vvals);
    hipLaunchKernelGGL(k6_softmax, dim3(NB), dim3(256), 0, stream, scores, vvals, out);
}

// Round 2
// 163.074 us; speedup vs baseline: 1.3770x; 1.3770x over previous
//
#include <hip/hip_runtime.h>
#include <math.h>

#define NB 32
#define LQ 2048
#define LK 2048
#define HD 1024
#define AD 512
#define QCH 32   // q-chunks for first-stage query reduction

// ---------------- K1: partial[qc][b][h] = sum over q-chunk of query ----------------
// 1024 blocks (4 blocks/CU, 16 waves/CU), 64 rows per block, 2-row unroll.
__global__ void __launch_bounds__(256) k1_qreduce(const float* __restrict__ query,
                                                 float* __restrict__ partial) {
    int bid = blockIdx.x;            // NB*QCH = 1024 blocks
    int b = bid / QCH, qc = bid % QCH;
    int t = threadIdx.x;             // 256 threads -> one float4 column each (HD=1024)
    const int QPC = LQ / QCH;        // 64 rows per chunk
    float4 a0 = {0.f, 0.f, 0.f, 0.f};
    float4 a1 = {0.f, 0.f, 0.f, 0.f};
    const float4* src = (const float4*)(query + ((size_t)b * LQ + (size_t)qc * QPC) * HD);
    for (int q = 0; q < QPC; q += 2) {
        float4 v0 = src[(size_t)q * (HD / 4) + t];
        float4 v1 = src[(size_t)(q + 1) * (HD / 4) + t];
        a0.x += v0.x; a0.y += v0.y; a0.z += v0.z; a0.w += v0.w;
        a1.x += v1.x; a1.y += v1.y; a1.z += v1.z; a1.w += v1.w;
    }
    float4 acc = {a0.x + a1.x, a0.y + a1.y, a0.z + a1.z, a0.w + a1.w};
    float4* dst = (float4*)(partial + ((size_t)qc * NB + b) * HD);
    dst[t] = acc;
}

// ---------------- K2: s_q[b][h] = sum over qc of partial ----------------
__global__ void __launch_bounds__(256) k2_qreduce2(const float* __restrict__ partial,
                                                   float* __restrict__ s_q) {
    int t = blockIdx.x * blockDim.x + threadIdx.x;   // NB*HD = 32768
    float acc = 0.f;
    for (int qc = 0; qc < QCH; ++qc) acc += partial[(size_t)qc * NB * HD + t];
    s_q[t] = acc;
}

// ---------------- K3: qsum[b][a] = s_q[b]·Wq[:,a] + LQ*bq[a] ----------------
// 4 independent f64 accumulators to break the dependent-add chain.
__global__ void __launch_bounds__(256) k3_qsum(const float* __restrict__ s_q,
                                               const float* __restrict__ Wq,
                                               const float* __restrict__ bq,
                                               float* __restrict__ qsum) {
    int t = blockIdx.x * blockDim.x + threadIdx.x;   // NB*AD = 16384
    int b = t / AD, a = t % AD;
    const float* sr = s_q + (size_t)b * HD;
    const float* wp = Wq + a;
    double c0 = 0.0, c1 = 0.0, c2 = 0.0, c3 = 0.0;
    for (int h = 0; h < HD; h += 4) {
        c0 += (double)sr[h]     * (double)wp[(size_t)h * AD];
        c1 += (double)sr[h + 1] * (double)wp[(size_t)(h + 1) * AD];
        c2 += (double)sr[h + 2] * (double)wp[(size_t)(h + 2) * AD];
        c3 += (double)sr[h + 3] * (double)wp[(size_t)(h + 3) * AD];
    }
    qsum[t] = (float)(((c0 + c1) + (c2 + c3)) + (double)LQ * (double)bq[a]);
}

// ---------------- K4: wave-per-row coalesced dots ----------------
// wave widx < NB*HD          : wk_eff[b][h] = qsum[b]·Wk[h,:]
// wave widx < NB*HD+HD       : wv_eff[h]    = Wk[h,:]·Wv
// wave widx == NB*HD+HD      : c_v = bk·Wv + bv
__global__ void __launch_bounds__(256) k4_weff(const float* __restrict__ qsum,
                                               const float* __restrict__ Wk,
                                               const float* __restrict__ Wv,
                                               const float* __restrict__ bk,
                                               const float* __restrict__ bv,
                                               float* __restrict__ wk_eff,
                                               float* __restrict__ wv_eff,
                                               float* __restrict__ c_v) {
    int w = threadIdx.x >> 6, lane = threadIdx.x & 63;
    int widx = blockIdx.x * 4 + w;
    double acc = 0.0;
    if (widx < NB * HD) {
        int b = widx / HD, h = widx % HD;
        const float4* wr = (const float4*)(Wk + (size_t)h * AD);
        const float4* qs = (const float4*)(qsum + (size_t)b * AD);
        #pragma unroll
        for (int j = 0; j < 2; ++j) {
            int f = lane + 64 * j;                   // 0..127 covers AD/4
            float4 wv4 = wr[f];
            float4 q4  = qs[f];
            acc += (double)wv4.x * (double)q4.x + (double)wv4.y * (double)q4.y
                 + (double)wv4.z * (double)q4.z + (double)wv4.w * (double)q4.w;
        }
        #pragma unroll
        for (int off = 32; off > 0; off >>= 1) acc += __shfl_down(acc, off);
        if (lane == 0) wk_eff[widx] = (float)acc;
    } else if (widx < NB * HD + HD) {
        int h = widx - NB * HD;
        const float4* wr = (const float4*)(Wk + (size_t)h * AD);
        const float4* vv = (const float4*)(Wv);
        #pragma unroll
        for (int j = 0; j < 2; ++j) {
            int f = lane + 64 * j;
            float4 wv4 = wr[f];
            float4 v4  = vv[f];
            acc += (double)wv4.x * (double)v4.x + (double)wv4.y * (double)v4.y
                 + (double)wv4.z * (double)v4.z + (double)wv4.w * (double)v4.w;
        }
        #pragma unroll
        for (int off = 32; off > 0; off >>= 1) acc += __shfl_down(acc, off);
        if (lane == 0) wv_eff[h] = (float)acc;
    } else if (widx == NB * HD + HD) {
        const float4* br = (const float4*)(bk);
        const float4* vv = (const float4*)(Wv);
        #pragma unroll
        for (int j = 0; j < 2; ++j) {
            int f = lane + 64 * j;
            float4 b4 = br[f];
            float4 v4 = vv[f];
            acc += (double)b4.x * (double)v4.x + (double)b4.y * (double)v4.y
                 + (double)b4.z * (double)v4.z + (double)b4.w * (double)v4.w;
        }
        #pragma unroll
        for (int off = 32; off > 0; off >>= 1) acc += __shfl_down(acc, off);
        if (lane == 0) c_v[0] = (float)(acc + (double)bv[0]);
    }
}

// ---------------- K5: per (b,k): scores = key·wk_eff[b], vvals = key·wv_eff + c_v ----------------
// 2048 blocks; stage LDS once per block; each wave does 8 rows.
__global__ void __launch_bounds__(256) k5_scores(const float* __restrict__ key,
                                                 const float* __restrict__ wk_eff,
                                                 const float* __restrict__ wv_eff,
                                                 const float* __restrict__ c_v,
                                                 float* __restrict__ scores,
                                                 float* __restrict__ vvals) {
    __shared__ float lwk[HD];
    __shared__ float lwv[HD];
    int bid = blockIdx.x;            // NB * (LK/32) = 2048 blocks
    int b = bid >> 6;                // 64 blocks per batch
    int k0 = (bid & 63) * 32;        // 32 rows per block
    for (int i = threadIdx.x; i < HD; i += 256) {
        lwk[i] = wk_eff[(size_t)b * HD + i];
        lwv[i] = wv_eff[i];
    }
    __syncthreads();
    int w = threadIdx.x >> 6;
    int lane = threadIdx.x & 63;
    double cv = (double)c_v[0];
    const float4* lwk4 = (const float4*)lwk;
    const float4* lwv4 = (const float4*)lwv;
    for (int r = 0; r < 8; ++r) {
        int k = k0 + w * 8 + r;
        const float4* kr = (const float4*)(key + ((size_t)b * LK + k) * HD);
        double sc = 0.0, vv = 0.0;
        #pragma unroll
        for (int j = 0; j < 4; ++j) {
            int f = lane + 64 * j;   // float4 index 0..255
            float4 kv  = kr[f];
            float4 wk4 = lwk4[f];
            float4 wv4 = lwv4[f];
            sc += (double)kv.x * (double)wk4.x + (double)kv.y * (double)wk4.y
                + (double)kv.z * (double)wk4.z + (double)kv.w * (double)wk4.w;
            vv += (double)kv.x * (double)wv4.x + (double)kv.y * (double)wv4.y
                + (double)kv.z * (double)wv4.z + (double)kv.w * (double)wv4.w;
        }
        #pragma unroll
        for (int off = 32; off > 0; off >>= 1) {
            sc += __shfl_down(sc, off);
            vv += __shfl_down(vv, off);
        }
        if (lane == 0) {
            scores[(size_t)b * LK + k] = (float)sc;
            vvals[(size_t)b * LK + k]  = (float)(vv + cv);
        }
    }
}

// ---------------- K6: per b: softmax over scores, weighted sum of vvals ----------------
__global__ void __launch_bounds__(256) k6_softmax(const float* __restrict__ scores,
                                                  const float* __restrict__ vvals,
                                                  float* __restrict__ out) {
    int b = blockIdx.x;
    int t = threadIdx.x;             // 256
    __shared__ float smax_sh[4];
    __shared__ double num_sh[4], den_sh[4];
    const float* sr = scores + (size_t)b * LK;
    const float* vr = vvals  + (size_t)b * LK;
    float m = -INFINITY;
    for (int k = t; k < LK; k += 256) m = fmaxf(m, sr[k]);
    #pragma unroll
    for (int off = 32; off > 0; off >>= 1) m = fmaxf(m, __shfl_down(m, off));
    int w = t >> 6, lane = t & 63;
    if (lane == 0) smax_sh[w] = m;
    __syncthreads();
    float gm = fmaxf(fmaxf(smax_sh[0], smax_sh[1]), fmaxf(smax_sh[2], smax_sh[3]));
    double num = 0.0, den = 0.0;
    for (int k = t; k < LK; k += 256) {
        double e = exp((double)(sr[k] - gm));
        den += e;
        num += e * (double)vr[k];
    }
    #pragma unroll
    for (int off = 32; off > 0; off >>= 1) {
        num += __shfl_down(num, off);
        den += __shfl_down(den, off);
    }
    if (lane == 0) { num_sh[w] = num; den_sh[w] = den; }
    __syncthreads();
    if (t == 0) {
        double N = num_sh[0] + num_sh[1] + num_sh[2] + num_sh[3];
        double D = den_sh[0] + den_sh[1] + den_sh[2] + den_sh[3];
        out[b] = (float)(N / D);
    }
}

extern "C" void kernel_launch(void* const* d_in, const int* in_sizes, int n_in,
                              void* d_out, int out_size, void* d_ws, size_t ws_size,
                              hipStream_t stream) {
    const float* query = (const float*)d_in[0];
    const float* key   = (const float*)d_in[1];
    const float* Wq    = (const float*)d_in[2];
    const float* bq    = (const float*)d_in[3];
    const float* Wk    = (const float*)d_in[4];
    const float* bk    = (const float*)d_in[5];
    const float* Wv    = (const float*)d_in[6];
    const float* bv    = (const float*)d_in[7];
    float* out = (float*)d_out;

    float* ws = (float*)d_ws;
    size_t off = 0;
    float* partial = ws + off; off += (size_t)QCH * NB * HD;  // 1048576 floats (4 MB)
    float* s_q     = ws + off; off += (size_t)NB * HD;        // 32768
    float* qsum    = ws + off; off += (size_t)NB * AD;        // 16384
    float* wk_eff  = ws + off; off += (size_t)NB * HD;        // 32768
    float* wv_eff  = ws + off; off += (size_t)HD;             // 1024
    float* c_v     = ws + off; off += 1;
    float* scores  = ws + off; off += (size_t)NB * LK;        // 65536
    float* vvals   = ws + off; off += (size_t)NB * LK;        // 65536

    hipLaunchKernelGGL(k1_qreduce, dim3(NB * QCH), dim3(256), 0, stream, query, partial);
    hipLaunchKernelGGL(k2_qreduce2, dim3(NB * HD / 256), dim3(256), 0, stream, partial, s_q);
    hipLaunchKernelGGL(k3_qsum, dim3(NB * AD / 256), dim3(256), 0, stream, s_q, Wq, bq, qsum);
    hipLaunchKernelGGL(k4_weff, dim3((NB * HD + HD + 1 + 3) / 4), dim3(256), 0, stream,
                       qsum, Wk, Wv, bk, bv, wk_eff, wv_eff, c_v);
    hipLaunchKernelGGL(k5_scores, dim3(NB * (LK / 32)), dim3(256), 0, stream,
                       key, wk_eff, wv_eff, c_v, scores, vvals);
    hipLaunchKernelGGL(k6_softmax, dim3(NB), dim3(256), 0, stream, scores, vvals, out);
}

// Round 3
// 148.632 us; speedup vs baseline: 1.5108x; 1.0972x over previous
//
#include <hip/hip_runtime.h>
#include <math.h>

#define NB 32
#define LQ 2048
#define LK 2048
#define HD 1024
#define AD 512
#define QCH 32   // q-chunks for first-stage query reduction

// ---------------- K1: query partial reduction + (overlapped) wv_eff, c_v ----------------
// blocks 0..1023            : partial[qc][b][h] = sum over 64-row q-chunk
// blocks 1024..1039         : wv_eff[h] = Wk[h,:]·Wv   (wave-per-row, 16 rows/wave)
// block  1040               : c_v = bk·Wv + bv          (one wave)
__global__ void __launch_bounds__(256) k1_qreduce(const float* __restrict__ query,
                                                 const float* __restrict__ Wk,
                                                 const float* __restrict__ Wv,
                                                 const float* __restrict__ bk,
                                                 const float* __restrict__ bv,
                                                 float* __restrict__ partial,
                                                 float* __restrict__ wv_eff,
                                                 float* __restrict__ c_v) {
    int bid = blockIdx.x;
    if (bid < NB * QCH) {
        int b = bid / QCH, qc = bid % QCH;
        int t = threadIdx.x;             // 256 threads -> one float4 column each (HD=1024)
        const int QPC = LQ / QCH;        // 64 rows per chunk
        float4 a0 = {0.f, 0.f, 0.f, 0.f};
        float4 a1 = {0.f, 0.f, 0.f, 0.f};
        const float4* src = (const float4*)(query + ((size_t)b * LQ + (size_t)qc * QPC) * HD);
        for (int q = 0; q < QPC; q += 2) {
            float4 v0 = src[(size_t)q * (HD / 4) + t];
            float4 v1 = src[(size_t)(q + 1) * (HD / 4) + t];
            a0.x += v0.x; a0.y += v0.y; a0.z += v0.z; a0.w += v0.w;
            a1.x += v1.x; a1.y += v1.y; a1.z += v1.z; a1.w += v1.w;
        }
        float4 acc = {a0.x + a1.x, a0.y + a1.y, a0.z + a1.z, a0.w + a1.w};
        float4* dst = (float4*)(partial + ((size_t)qc * NB + b) * HD);
        dst[t] = acc;
    } else if (bid < NB * QCH + 16) {
        // wv_eff: 16 blocks x 4 waves = 64 waves, 16 rows each
        int w = threadIdx.x >> 6, lane = threadIdx.x & 63;
        int gw = (bid - NB * QCH) * 4 + w;           // 0..63
        const float4* vv = (const float4*)(Wv);
        for (int r = 0; r < 16; ++r) {
            int h = gw * 16 + r;
            const float4* wr = (const float4*)(Wk + (size_t)h * AD);
            double acc = 0.0;
            #pragma unroll
            for (int j = 0; j < 2; ++j) {
                int f = lane + 64 * j;               // 0..127 covers AD/4
                float4 w4 = wr[f];
                float4 v4 = vv[f];
                acc += (double)w4.x * (double)v4.x + (double)w4.y * (double)v4.y
                     + (double)w4.z * (double)v4.z + (double)w4.w * (double)v4.w;
            }
            #pragma unroll
            for (int off = 32; off > 0; off >>= 1) acc += __shfl_down(acc, off);
            if (lane == 0) wv_eff[h] = (float)acc;
        }
    } else {
        // c_v: single wave
        if (threadIdx.x < 64) {
            int lane = threadIdx.x;
            const float4* br = (const float4*)(bk);
            const float4* vv = (const float4*)(Wv);
            double acc = 0.0;
            #pragma unroll
            for (int j = 0; j < 2; ++j) {
                int f = lane + 64 * j;
                float4 b4 = br[f];
                float4 v4 = vv[f];
                acc += (double)b4.x * (double)v4.x + (double)b4.y * (double)v4.y
                     + (double)b4.z * (double)v4.z + (double)b4.w * (double)v4.w;
            }
            #pragma unroll
            for (int off = 32; off > 0; off >>= 1) acc += __shfl_down(acc, off);
            if (lane == 0) c_v[0] = (float)(acc + (double)bv[0]);
        }
    }
}

// ---------------- KB (fused k2+k3): s_q reduce + qsum ----------------
// 256 blocks: b = blockIdx/8, a-chunk of 64 = (blockIdx%8)*64.
// Phase A: s_q[b][:] into LDS (sum of 32 partial chunks).
// Phase B: qsum[b][a0..a0+63] = s_q·Wq[:,a] + LQ*bq[a], wave w covers h in [w*256,(w+1)*256).
__global__ void __launch_bounds__(256) kB_qsum(const float* __restrict__ partial,
                                               const float* __restrict__ Wq,
                                               const float* __restrict__ bq,
                                               float* __restrict__ qsum) {
    __shared__ float sq[HD];
    __shared__ double red[4][64];
    int b = blockIdx.x >> 3;
    int a0 = (blockIdx.x & 7) * 64;
    int t = threadIdx.x;

    // Phase A
    #pragma unroll
    for (int c = 0; c < 4; ++c) {
        int h = t + c * 256;
        float acc = 0.f;
        #pragma unroll 4
        for (int qc = 0; qc < QCH; ++qc)
            acc += partial[((size_t)qc * NB + b) * HD + h];
        sq[h] = acc;
    }
    __syncthreads();

    // Phase B
    int w = t >> 6, lane = t & 63;
    int a = a0 + lane;
    const float* wp = Wq + a;
    double c0 = 0.0, c1 = 0.0, c2 = 0.0, c3 = 0.0;
    int hbase = w * 256;
    for (int i = 0; i < 256; i += 4) {
        int h = hbase + i;
        c0 += (double)sq[h]     * (double)wp[(size_t)h * AD];
        c1 += (double)sq[h + 1] * (double)wp[(size_t)(h + 1) * AD];
        c2 += (double)sq[h + 2] * (double)wp[(size_t)(h + 2) * AD];
        c3 += (double)sq[h + 3] * (double)wp[(size_t)(h + 3) * AD];
    }
    red[w][lane] = ((c0 + c1) + (c2 + c3));
    __syncthreads();
    if (t < 64) {
        double s = red[0][t] + red[1][t] + red[2][t] + red[3][t];
        qsum[(size_t)b * AD + a0 + t] = (float)(s + (double)LQ * (double)bq[a0 + t]);
    }
}

// ---------------- K4: wk_eff[b][h] = qsum[b]·Wk[h,:] (wave-per-row) ----------------
__global__ void __launch_bounds__(256) k4_weff(const float* __restrict__ qsum,
                                               const float* __restrict__ Wk,
                                               float* __restrict__ wk_eff) {
    int w = threadIdx.x >> 6, lane = threadIdx.x & 63;
    int widx = blockIdx.x * 4 + w;                   // 0..NB*HD-1
    int b = widx >> 10, h = widx & (HD - 1);
    const float4* wr = (const float4*)(Wk + (size_t)h * AD);
    const float4* qs = (const float4*)(qsum + (size_t)b * AD);
    double acc = 0.0;
    #pragma unroll
    for (int j = 0; j < 2; ++j) {
        int f = lane + 64 * j;
        float4 w4 = wr[f];
        float4 q4 = qs[f];
        acc += (double)w4.x * (double)q4.x + (double)w4.y * (double)q4.y
             + (double)w4.z * (double)q4.z + (double)w4.w * (double)q4.w;
    }
    #pragma unroll
    for (int off = 32; off > 0; off >>= 1) acc += __shfl_down(acc, off);
    if (lane == 0) wk_eff[widx] = (float)acc;
}

// ---------------- K5: per (b,k): scores = key·wk_eff[b], vvals = key·wv_eff + c_v ----------------
__global__ void __launch_bounds__(256) k5_scores(const float* __restrict__ key,
                                                 const float* __restrict__ wk_eff,
                                                 const float* __restrict__ wv_eff,
                                                 const float* __restrict__ c_v,
                                                 float* __restrict__ scores,
                                                 float* __restrict__ vvals) {
    __shared__ float lwk[HD];
    __shared__ float lwv[HD];
    int bid = blockIdx.x;            // NB * (LK/32) = 2048 blocks
    int b = bid >> 6;                // 64 blocks per batch
    int k0 = (bid & 63) * 32;        // 32 rows per block
    for (int i = threadIdx.x; i < HD; i += 256) {
        lwk[i] = wk_eff[(size_t)b * HD + i];
        lwv[i] = wv_eff[i];
    }
    __syncthreads();
    int w = threadIdx.x >> 6;
    int lane = threadIdx.x & 63;
    double cv = (double)c_v[0];
    const float4* lwk4 = (const float4*)lwk;
    const float4* lwv4 = (const float4*)lwv;
    for (int r = 0; r < 8; ++r) {
        int k = k0 + w * 8 + r;
        const float4* kr = (const float4*)(key + ((size_t)b * LK + k) * HD);
        double sc = 0.0, vv = 0.0;
        #pragma unroll
        for (int j = 0; j < 4; ++j) {
            int f = lane + 64 * j;   // float4 index 0..255
            float4 kv  = kr[f];
            float4 wk4 = lwk4[f];
            float4 wv4 = lwv4[f];
            sc += (double)kv.x * (double)wk4.x + (double)kv.y * (double)wk4.y
                + (double)kv.z * (double)wk4.z + (double)kv.w * (double)wk4.w;
            vv += (double)kv.x * (double)wv4.x + (double)kv.y * (double)wv4.y
                + (double)kv.z * (double)wv4.z + (double)kv.w * (double)wv4.w;
        }
        #pragma unroll
        for (int off = 32; off > 0; off >>= 1) {
            sc += __shfl_down(sc, off);
            vv += __shfl_down(vv, off);
        }
        if (lane == 0) {
            scores[(size_t)b * LK + k] = (float)sc;
            vvals[(size_t)b * LK + k]  = (float)(vv + cv);
        }
    }
}

// ---------------- K6: per b: softmax over scores, weighted sum of vvals ----------------
__global__ void __launch_bounds__(256) k6_softmax(const float* __restrict__ scores,
                                                  const float* __restrict__ vvals,
                                                  float* __restrict__ out) {
    int b = blockIdx.x;
    int t = threadIdx.x;             // 256
    __shared__ float smax_sh[4];
    __shared__ double num_sh[4], den_sh[4];
    const float* sr = scores + (size_t)b * LK;
    const float* vr = vvals  + (size_t)b * LK;
    float m = -INFINITY;
    for (int k = t; k < LK; k += 256) m = fmaxf(m, sr[k]);
    #pragma unroll
    for (int off = 32; off > 0; off >>= 1) m = fmaxf(m, __shfl_down(m, off));
    int w = t >> 6, lane = t & 63;
    if (lane == 0) smax_sh[w] = m;
    __syncthreads();
    float gm = fmaxf(fmaxf(smax_sh[0], smax_sh[1]), fmaxf(smax_sh[2], smax_sh[3]));
    double num = 0.0, den = 0.0;
    for (int k = t; k < LK; k += 256) {
        double e = exp((double)(sr[k] - gm));
        den += e;
        num += e * (double)vr[k];
    }
    #pragma unroll
    for (int off = 32; off > 0; off >>= 1) {
        num += __shfl_down(num, off);
        den += __shfl_down(den, off);
    }
    if (lane == 0) { num_sh[w] = num; den_sh[w] = den; }
    __syncthreads();
    if (t == 0) {
        double N = num_sh[0] + num_sh[1] + num_sh[2] + num_sh[3];
        double D = den_sh[0] + den_sh[1] + den_sh[2] + den_sh[3];
        out[b] = (float)(N / D);
    }
}

extern "C" void kernel_launch(void* const* d_in, const int* in_sizes, int n_in,
                              void* d_out, int out_size, void* d_ws, size_t ws_size,
                              hipStream_t stream) {
    const float* query = (const float*)d_in[0];
    const float* key   = (const float*)d_in[1];
    const float* Wq    = (const float*)d_in[2];
    const float* bq    = (const float*)d_in[3];
    const float* Wk    = (const float*)d_in[4];
    const float* bk    = (const float*)d_in[5];
    const float* Wv    = (const float*)d_in[6];
    const float* bv    = (const float*)d_in[7];
    float* out = (float*)d_out;

    float* ws = (float*)d_ws;
    size_t off = 0;
    float* partial = ws + off; off += (size_t)QCH * NB * HD;  // 4 MB
    float* qsum    = ws + off; off += (size_t)NB * AD;
    float* wk_eff  = ws + off; off += (size_t)NB * HD;
    float* wv_eff  = ws + off; off += (size_t)HD;
    float* c_v     = ws + off; off += 1;
    float* scores  = ws + off; off += (size_t)NB * LK;
    float* vvals   = ws + off; off += (size_t)NB * LK;

    hipLaunchKernelGGL(k1_qreduce, dim3(NB * QCH + 16 + 1), dim3(256), 0, stream,
                       query, Wk, Wv, bk, bv, partial, wv_eff, c_v);
    hipLaunchKernelGGL(kB_qsum, dim3(NB * 8), dim3(256), 0, stream, partial, Wq, bq, qsum);
    hipLaunchKernelGGL(k4_weff, dim3(NB * HD / 4), dim3(256), 0, stream, qsum, Wk, wk_eff);
    hipLaunchKernelGGL(k5_scores, dim3(NB * (LK / 32)), dim3(256), 0, stream,
                       key, wk_eff, wv_eff, c_v, scores, vvals);
    hipLaunchKernelGGL(k6_softmax, dim3(NB), dim3(256), 0, stream, scores, vvals, out);
}